// Round 4
// baseline (251.877 us; speedup 1.0000x reference)
//
#include <hip/hip_runtime.h>

// Channelwise Sorensen-Dice over (1,3,96,256,256) fp32; each channel is a
// contiguous 6,291,456-float block (1,572,864 float4). Need per-channel
// sum(x*t), sum(x*x), sum(t*t); loss = sum_c -2*num/max(den,eps).
//
// R4 strategy: plain VGPR float4 loads (the proven-fast path on gfx950),
// 2048 blocks/channel (24 blocks/CU -> full occupancy), exactly 3 float4
// per array per thread, all 6 loads forced in-flight before any use via
// sched_barrier(0) (stops the compiler's VGPR-minimizing re-interleave
// that killed R2).
#define NCH 3
#define PER_CH4 1572864
#define BPC 2048                    // blocks per channel
#define THREADS 256
#define POS (BPC * THREADS)         // 524288 float4 positions per sweep
#define EPS 1e-6f

// acc layout in d_ws: acc[ch*3 + 0] = sum(x*t), +1 = sum(x*x), +2 = sum(t*t)
__global__ void __launch_bounds__(256)
dice_reduce_kernel(const float4* __restrict__ x, const float4* __restrict__ t,
                   float* __restrict__ acc) {
    const int ch = blockIdx.y;
    const size_t p = (size_t)ch * PER_CH4 + (size_t)blockIdx.x * THREADS + threadIdx.x;

    // Issue all 6 loads (96 B/thread, 6 KB/wave) back-to-back.
    float4 x0 = x[p];
    float4 x1 = x[p + POS];
    float4 x2 = x[p + 2 * POS];
    float4 t0 = t[p];
    float4 t1 = t[p + POS];
    float4 t2 = t[p + 2 * POS];
    // Fence: nothing below may be hoisted above (keeps all loads in flight).
    __builtin_amdgcn_sched_barrier(0);

    float sxt = x0.x * t0.x + x0.y * t0.y + x0.z * t0.z + x0.w * t0.w
              + x1.x * t1.x + x1.y * t1.y + x1.z * t1.z + x1.w * t1.w
              + x2.x * t2.x + x2.y * t2.y + x2.z * t2.z + x2.w * t2.w;
    float sxx = x0.x * x0.x + x0.y * x0.y + x0.z * x0.z + x0.w * x0.w
              + x1.x * x1.x + x1.y * x1.y + x1.z * x1.z + x1.w * x1.w
              + x2.x * x2.x + x2.y * x2.y + x2.z * x2.z + x2.w * x2.w;
    float stt = t0.x * t0.x + t0.y * t0.y + t0.z * t0.z + t0.w * t0.w
              + t1.x * t1.x + t1.y * t1.y + t1.z * t1.z + t1.w * t1.w
              + t2.x * t2.x + t2.y * t2.y + t2.z * t2.z + t2.w * t2.w;

    // Wave-64 butterfly reduction
    for (int off = 32; off > 0; off >>= 1) {
        sxt += __shfl_xor(sxt, off, 64);
        sxx += __shfl_xor(sxx, off, 64);
        stt += __shfl_xor(stt, off, 64);
    }

    // Cross-wave reduction via LDS (4 waves), then one atomic per block per sum
    __shared__ float red[3][4];
    const int lane = threadIdx.x & 63;
    const int wave = threadIdx.x >> 6;
    if (lane == 0) {
        red[0][wave] = sxt;
        red[1][wave] = sxx;
        red[2][wave] = stt;
    }
    __syncthreads();
    if (threadIdx.x == 0) {
        float bxt = red[0][0] + red[0][1] + red[0][2] + red[0][3];
        float bxx = red[1][0] + red[1][1] + red[1][2] + red[1][3];
        float btt = red[2][0] + red[2][1] + red[2][2] + red[2][3];
        atomicAdd(&acc[ch * 3 + 0], bxt);
        atomicAdd(&acc[ch * 3 + 1], bxx);
        atomicAdd(&acc[ch * 3 + 2], btt);
    }
}

__global__ void dice_finalize_kernel(const float* __restrict__ acc,
                                     float* __restrict__ out) {
    if (threadIdx.x == 0 && blockIdx.x == 0) {
        float loss = 0.f;
        for (int c = 0; c < NCH; ++c) {
            float num = acc[c * 3 + 0];
            float den = acc[c * 3 + 1] + acc[c * 3 + 2];
            loss += -2.f * (num / fmaxf(den, EPS));
        }
        out[0] = loss;
    }
}

extern "C" void kernel_launch(void* const* d_in, const int* in_sizes, int n_in,
                              void* d_out, int out_size, void* d_ws, size_t ws_size,
                              hipStream_t stream) {
    const float4* x = (const float4*)d_in[0];
    const float4* t = (const float4*)d_in[1];
    float* acc = (float*)d_ws;
    float* out = (float*)d_out;

    // Workspace is poisoned (0xAA) and never re-poisoned between replays:
    // zero the 9 accumulators every call.
    hipMemsetAsync(acc, 0, NCH * 3 * sizeof(float), stream);

    dim3 grid(BPC, NCH);
    dice_reduce_kernel<<<grid, THREADS, 0, stream>>>(x, t, acc);
    dice_finalize_kernel<<<1, 64, 0, stream>>>(acc, out);
}

// Round 5
// 29.459 us; speedup vs baseline: 8.5502x; 8.5502x over previous
//
#include <hip/hip_runtime.h>

// Channelwise Sorensen-Dice over (1,3,96,256,256) fp32; each channel is a
// contiguous 6,291,456-float block. Per-channel sum(x*t), sum(x*x), sum(t*t);
// loss = sum_c -2*num/max(den,eps).
//
// R5: R3's LDS-DMA streaming kernel UNCHANGED, but no atomics: blocks write
// partials to distinct slots (contention-free), a 9-wave finalize kernel
// reduces them. (R1-R4 fit time = streaming + 10ns * n_atomics: the 9 floats
// shared one cache line and serialized the whole kernel.)
#define NCH 3
#define PER_CH 6291456
#define THREADS 256
#define WPB 4                       // waves per block
#define GRIDX 512                   // blocks per channel
#define NWX (GRIDX * WPB)           // 2048 waves per channel
#define CHUNK 512                   // floats per array per chunk (2 KB)
#define CHUNKS_PER_WAVE 6           // PER_CH / CHUNK / NWX == 6 exactly
#define EPS 1e-6f

__device__ __forceinline__ void gload16(const float* g, float* l) {
    // dwordx4 direct global->LDS: lane i's 16B land at l + i*16.
    __builtin_amdgcn_global_load_lds(
        (__attribute__((address_space(1))) void*)g,
        (__attribute__((address_space(3))) void*)l,
        16, 0, 0);
}

// partial layout in d_ws: partial[(ch*3+k)*GRIDX + blockIdx.x], k=0:xt 1:xx 2:tt
__global__ void __launch_bounds__(256)
dice_partial_kernel(const float* __restrict__ x, const float* __restrict__ t,
                    float* __restrict__ partial) {
    __shared__ __align__(16) float lx[WPB][CHUNK];
    __shared__ __align__(16) float lt[WPB][CHUNK];
    __shared__ float red[3][WPB];

    const int lane = threadIdx.x & 63;
    const int wave = threadIdx.x >> 6;
    const int ch = blockIdx.y;
    const int gwx = blockIdx.x * WPB + wave;
    const size_t ch_base = (size_t)ch * PER_CH;

    float* lxw = &lx[wave][0];
    float* ltw = &lt[wave][0];

    float sxt = 0.f, sxx = 0.f, stt = 0.f;

#pragma unroll 1
    for (int j = 0; j < CHUNKS_PER_WAVE; ++j) {
        const size_t gbase = ch_base + (size_t)(gwx + j * NWX) * CHUNK;
        const float* gx = x + gbase + lane * 4;   // lane*16 bytes
        const float* gt = t + gbase + lane * 4;
        gload16(gx,       lxw);         // floats [0,256)
        gload16(gx + 256, lxw + 256);   // floats [256,512)
        gload16(gt,       ltw);
        gload16(gt + 256, ltw + 256);
        asm volatile("s_waitcnt vmcnt(0)" ::: "memory");

        float4 x0 = *reinterpret_cast<const float4*>(lxw + lane * 4);
        float4 x1 = *reinterpret_cast<const float4*>(lxw + 256 + lane * 4);
        float4 t0 = *reinterpret_cast<const float4*>(ltw + lane * 4);
        float4 t1 = *reinterpret_cast<const float4*>(ltw + 256 + lane * 4);

        sxt += x0.x * t0.x + x0.y * t0.y + x0.z * t0.z + x0.w * t0.w
             + x1.x * t1.x + x1.y * t1.y + x1.z * t1.z + x1.w * t1.w;
        sxx += x0.x * x0.x + x0.y * x0.y + x0.z * x0.z + x0.w * x0.w
             + x1.x * x1.x + x1.y * x1.y + x1.z * x1.z + x1.w * x1.w;
        stt += t0.x * t0.x + t0.y * t0.y + t0.z * t0.z + t0.w * t0.w
             + t1.x * t1.x + t1.y * t1.y + t1.z * t1.z + t1.w * t1.w;
    }

    // Wave-64 butterfly reduction
    for (int off = 32; off > 0; off >>= 1) {
        sxt += __shfl_xor(sxt, off, 64);
        sxx += __shfl_xor(sxx, off, 64);
        stt += __shfl_xor(stt, off, 64);
    }

    // Cross-wave reduction (4 waves), then contention-free plain stores.
    if (lane == 0) {
        red[0][wave] = sxt;
        red[1][wave] = sxx;
        red[2][wave] = stt;
    }
    __syncthreads();
    if (threadIdx.x == 0) {
        float bxt = red[0][0] + red[0][1] + red[0][2] + red[0][3];
        float bxx = red[1][0] + red[1][1] + red[1][2] + red[1][3];
        float btt = red[2][0] + red[2][1] + red[2][2] + red[2][3];
        partial[(ch * 3 + 0) * GRIDX + blockIdx.x] = bxt;
        partial[(ch * 3 + 1) * GRIDX + blockIdx.x] = bxx;
        partial[(ch * 3 + 2) * GRIDX + blockIdx.x] = btt;
    }
}

// 9 waves (576 threads): wave w reduces row w of partial[9][GRIDX].
__global__ void __launch_bounds__(576)
dice_final_kernel(const float* __restrict__ partial, float* __restrict__ out) {
    __shared__ float red[9];
    const int w = threadIdx.x >> 6;     // 0..8
    const int lane = threadIdx.x & 63;

    float s = 0.f;
    const float* row = partial + w * GRIDX;
#pragma unroll
    for (int i = 0; i < GRIDX / 64; ++i) s += row[lane + i * 64];
    for (int off = 32; off > 0; off >>= 1) s += __shfl_xor(s, off, 64);
    if (lane == 0) red[w] = s;
    __syncthreads();

    if (threadIdx.x == 0) {
        float loss = 0.f;
        for (int c = 0; c < NCH; ++c) {
            float num = red[c * 3 + 0];
            float den = red[c * 3 + 1] + red[c * 3 + 2];
            loss += -2.f * (num / fmaxf(den, EPS));
        }
        out[0] = loss;
    }
}

extern "C" void kernel_launch(void* const* d_in, const int* in_sizes, int n_in,
                              void* d_out, int out_size, void* d_ws, size_t ws_size,
                              hipStream_t stream) {
    const float* x = (const float*)d_in[0];
    const float* t = (const float*)d_in[1];
    float* partial = (float*)d_ws;      // 9*GRIDX floats = 18 KB, overwritten fully each call
    float* out = (float*)d_out;

    dim3 grid(GRIDX, NCH);
    dice_partial_kernel<<<grid, THREADS, 0, stream>>>(x, t, partial);
    dice_final_kernel<<<1, 576, 0, stream>>>(partial, out);
}